// Round 7
// baseline (147.371 us; speedup 1.0000x reference)
//
#include <hip/hip_runtime.h>
#include <hip/hip_cooperative_groups.h>

namespace cg = cooperative_groups;

#define D 64
#define H 8
#define LSEQ 2048
#define KMAX 64
#define NCODES 256   // 2^H
#define NPOS 8192    // B * LSEQ (B=4)

// ---------------------------------------------------------------------------
// Single cooperative kernel: grid = 256 blocks x 256 threads (1 block/CU,
// trivially co-resident).
//
// Phase 1: threads 0..2*NPOS-1 compute one position's LSH code each.
//   code = sum_h ( (sum_{d: x[d]>0} W[d][h]) > 0 ) << h, fp32 sequential over
//   d (matches reference accumulation order — absmax 0 every round).
//   Query codes -> int array; key codes -> permuted byte array where the byte
//   for local pos (i*256 + j*64 + lane) lives at (i*256 + lane*4 + j), so a
//   single uint load per lane covers 4 ascending 64-chunks.
//
// grid.sync() with device-scope fences on both sides (cross-XCD L2, G16).
//
// Phase 2: 1024 waves x 8 queries each. The 8 permuted code-uints are loaded
//   ONCE per wave (all 8 queries share a batch since 2048 % 8 == 0) and
//   reused; per query: 32 ballot stream-compaction steps into a -1-padded
//   private LDS row, then one coalesced 256B store.
// ---------------------------------------------------------------------------
__global__ void __launch_bounds__(256)
fused_kernel(const float* __restrict__ query,
             const float* __restrict__ key,
             const float* __restrict__ W,
             int* __restrict__ q_code,            // ws: [NPOS] ints
             unsigned char* __restrict__ kperm,   // ws: [NPOS] bytes (permuted)
             int* __restrict__ out) {             // [NPOS][KMAX]
    __shared__ float Ws[D * H];
    __shared__ int rows[4][KMAX];

    int tid = threadIdx.x;
    for (int i = tid; i < D * H; i += blockDim.x) Ws[i] = W[i];
    __syncthreads();

    // ---------------- Phase 1: codes ----------------
    int t = blockIdx.x * blockDim.x + tid;
    if (t < 2 * NPOS) {
        const float* xp = (t < NPOS) ? (query + (size_t)t * D)
                                     : (key + (size_t)(t - NPOS) * D);
        float4 s0 = {0.f, 0.f, 0.f, 0.f};
        float4 s1 = {0.f, 0.f, 0.f, 0.f};
        for (int d4 = 0; d4 < D / 4; ++d4) {
            float4 xv = ((const float4*)xp)[d4];
            const float* x4 = (const float*)&xv;
#pragma unroll
            for (int k = 0; k < 4; ++k) {
                if (x4[k] > 0.0f) {
                    int d = d4 * 4 + k;
                    float4 w0 = *(const float4*)&Ws[d * H + 0];   // LDS broadcast
                    float4 w1 = *(const float4*)&Ws[d * H + 4];
                    s0.x += w0.x; s0.y += w0.y; s0.z += w0.z; s0.w += w0.w;
                    s1.x += w1.x; s1.y += w1.y; s1.z += w1.z; s1.w += w1.w;
                }
            }
        }
        int c = 0;
        c |= (s0.x > 0.0f) ? 1   : 0;
        c |= (s0.y > 0.0f) ? 2   : 0;
        c |= (s0.z > 0.0f) ? 4   : 0;
        c |= (s0.w > 0.0f) ? 8   : 0;
        c |= (s1.x > 0.0f) ? 16  : 0;
        c |= (s1.y > 0.0f) ? 32  : 0;
        c |= (s1.z > 0.0f) ? 64  : 0;
        c |= (s1.w > 0.0f) ? 128 : 0;

        if (t < NPOS) {
            q_code[t] = c;
        } else {
            int kk   = t - NPOS;
            int b    = kk >> 11;            // LSEQ = 2048
            int l    = kk & (LSEQ - 1);
            int lane = l & 63;
            int j    = (l >> 6) & 3;
            int i4   = l >> 8;
            kperm[(b << 11) + (i4 << 8) + (lane << 2) + j] = (unsigned char)c;
        }
    }

    __threadfence();            // release: flush phase-1 writes (cross-XCD)
    cg::this_grid().sync();
    __threadfence();            // acquire: invalidate before phase-2 reads

    // ---------------- Phase 2: scan + emit ----------------
    int wave = tid >> 6;
    int lane = tid & 63;
    int w = blockIdx.x * 4 + wave;          // 0..1023
    int q0 = w * 8;                         // 8 queries per wave, same batch
    int b = q0 >> 11;

    const unsigned int* kp = (const unsigned int*)kperm + (size_t)b * (LSEQ / 4) + lane;
    unsigned int v[LSEQ / 256];             // 8 uints = 32 codes per lane
#pragma unroll
    for (int i = 0; i < LSEQ / 256; ++i) v[i] = kp[i * 64];   // all in flight

    int* row = rows[wave];
    unsigned long long lt_mask = (lane == 63) ? 0x7FFFFFFFFFFFFFFFull
                                              : ((1ull << lane) - 1ull);
    for (int qq = 0; qq < 8; ++qq) {
        int q = q0 + qq;
        int c = q_code[q];                  // wave-uniform broadcast load
        row[lane] = -1;
        int base = 0;
#pragma unroll
        for (int i = 0; i < LSEQ / 256; ++i) {
            unsigned int w4 = v[i];
#pragma unroll
            for (int j = 0; j < 4; ++j) {
                int ci = (int)((w4 >> (8 * j)) & 0xFFu);
                unsigned long long mask = __ballot(ci == c);
                if (ci == c) {
                    int rank = base + __popcll(mask & lt_mask);
                    if (rank < KMAX) row[rank] = i * 256 + j * 64 + lane;
                }
                base += __popcll(mask);
            }
        }
        out[(size_t)q * KMAX + lane] = row[lane];   // 256B coalesced
    }
}

extern "C" void kernel_launch(void* const* d_in, const int* in_sizes, int n_in,
                              void* d_out, int out_size, void* d_ws, size_t ws_size,
                              hipStream_t stream) {
    const float* query = (const float*)d_in[0];
    const float* key   = (const float*)d_in[1];
    const float* W     = (const float*)d_in[2];
    // d_in[3] = head_idx (unused)
    (void)in_sizes; (void)n_in; (void)out_size; (void)ws_size;

    int* q_code = (int*)d_ws;                                  // NPOS ints
    unsigned char* kperm = (unsigned char*)(q_code + NPOS);    // NPOS bytes
    int* out = (int*)d_out;

    void* args[] = {(void*)&query, (void*)&key, (void*)&W,
                    (void*)&q_code, (void*)&kperm, (void*)&out};
    hipLaunchCooperativeKernel((const void*)fused_kernel,
                               dim3(256), dim3(256), args, 0, stream);
}

// Round 8
// 83.832 us; speedup vs baseline: 1.7579x; 1.7579x over previous
//
#include <hip/hip_runtime.h>

#define D 64
#define H 8
#define LSEQ 2048
#define KMAX 64
#define NCODES 256   // 2^H

// ---------------------------------------------------------------------------
// Kernel 1: LSH codes for BOTH query and key positions.
// code = sum_h ( (sum_{d: x[d]>0} W[d][h]) > 0 ) << h
// Sequential over d (matches reference accumulation order — absmax has been
// exactly 0 every round; do not re-associate).
// Query codes -> int array. Key codes -> PERMUTED byte array laid out so the
// scan kernel's uint load yields 4 ascending 64-chunks per lane:
//   byte for local pos (i*256 + j*64 + lane) lives at (i*256 + lane*4 + j).
// 64-thread blocks -> 256 blocks, one per CU.
// NOTE (R7 lesson): do NOT fuse these two kernels with a cooperative
// grid.sync — it cost ~65 µs on gfx950 (256 blocks spinning on device-scope
// atomics across non-coherent XCD L2s). Two launches is ~100x cheaper.
// ---------------------------------------------------------------------------
__global__ void __launch_bounds__(64)
code_kernel(const float* __restrict__ query,
            const float* __restrict__ key,
            const float* __restrict__ W,
            int* __restrict__ q_code,            // [n_pos]
            unsigned char* __restrict__ kperm,   // [n_pos] permuted bytes
            int n_pos) {
    __shared__ float Ws[D * H];
    for (int i = threadIdx.x; i < D * H; i += blockDim.x) Ws[i] = W[i];
    __syncthreads();

    int t = blockIdx.x * blockDim.x + threadIdx.x;
    if (t >= 2 * n_pos) return;

    const float* xp = (t < n_pos) ? (query + (size_t)t * D)
                                  : (key + (size_t)(t - n_pos) * D);
    float4 s0 = {0.f, 0.f, 0.f, 0.f};
    float4 s1 = {0.f, 0.f, 0.f, 0.f};

    for (int d4 = 0; d4 < D / 4; ++d4) {
        float4 xv = ((const float4*)xp)[d4];
        const float* x4 = (const float*)&xv;
#pragma unroll
        for (int k = 0; k < 4; ++k) {
            if (x4[k] > 0.0f) {
                int d = d4 * 4 + k;
                float4 w0 = *(const float4*)&Ws[d * H + 0];   // LDS broadcast
                float4 w1 = *(const float4*)&Ws[d * H + 4];
                s0.x += w0.x; s0.y += w0.y; s0.z += w0.z; s0.w += w0.w;
                s1.x += w1.x; s1.y += w1.y; s1.z += w1.z; s1.w += w1.w;
            }
        }
    }
    int c = 0;
    c |= (s0.x > 0.0f) ? 1   : 0;
    c |= (s0.y > 0.0f) ? 2   : 0;
    c |= (s0.z > 0.0f) ? 4   : 0;
    c |= (s0.w > 0.0f) ? 8   : 0;
    c |= (s1.x > 0.0f) ? 16  : 0;
    c |= (s1.y > 0.0f) ? 32  : 0;
    c |= (s1.z > 0.0f) ? 64  : 0;
    c |= (s1.w > 0.0f) ? 128 : 0;

    if (t < n_pos) {
        q_code[t] = c;
    } else {
        int kk   = t - n_pos;
        int b    = kk >> 11;            // LSEQ = 2048
        int l    = kk & (LSEQ - 1);
        int lane = l & 63;
        int j    = (l >> 6) & 3;
        int i4   = l >> 8;
        kperm[(b << 11) + (i4 << 8) + (lane << 2) + j] = (unsigned char)c;
    }
}

// ---------------------------------------------------------------------------
// Kernel 2 (fused scan + emit): one WAVE per 8 QUERIES (1024 waves, 256
// blocks). The 8 permuted code-uints (32 codes/lane) are loaded ONCE per
// wave — all in flight, no early exit — and reused across the 8 queries.
// Per query: 32 ballot stream-compaction steps rank the first <=KMAX
// ascending matches into a -1-padded private LDS row, then one coalesced
// 256B store.
// ---------------------------------------------------------------------------
__global__ void __launch_bounds__(256)
scan_emit_kernel(const int* __restrict__ q_code,          // [B*LSEQ]
                 const unsigned int* __restrict__ kperm,  // [B][LSEQ/4]
                 int* __restrict__ out) {                 // [B*LSEQ][KMAX]
    __shared__ int rows[4][KMAX];
    int wave = threadIdx.x >> 6;
    int lane = threadIdx.x & 63;
    int w = blockIdx.x * 4 + wave;       // 0..1023
    int q0 = w * 8;                      // 8 queries per wave, same batch
    int b = q0 >> 11;                    // LSEQ = 2048

    const unsigned int* kp = kperm + (size_t)b * (LSEQ / 4) + lane;
    unsigned int v[LSEQ / 256];          // 8 uints = 32 codes per lane
#pragma unroll
    for (int i = 0; i < LSEQ / 256; ++i) v[i] = kp[i * 64];   // all in flight

    int* row = rows[wave];
    unsigned long long lt_mask = (lane == 63) ? 0x7FFFFFFFFFFFFFFFull
                                              : ((1ull << lane) - 1ull);
    for (int qq = 0; qq < 8; ++qq) {
        int q = q0 + qq;
        int c = q_code[q];               // wave-uniform broadcast load
        row[lane] = -1;
        int base = 0;
#pragma unroll
        for (int i = 0; i < LSEQ / 256; ++i) {
            unsigned int w4 = v[i];
#pragma unroll
            for (int j = 0; j < 4; ++j) {
                int ci = (int)((w4 >> (8 * j)) & 0xFFu);
                unsigned long long mask = __ballot(ci == c);
                if (ci == c) {
                    int rank = base + __popcll(mask & lt_mask);
                    if (rank < KMAX) row[rank] = i * 256 + j * 64 + lane;
                }
                base += __popcll(mask);
            }
        }
        out[(size_t)q * KMAX + lane] = row[lane];   // 256B coalesced
    }
}

extern "C" void kernel_launch(void* const* d_in, const int* in_sizes, int n_in,
                              void* d_out, int out_size, void* d_ws, size_t ws_size,
                              hipStream_t stream) {
    const float* query = (const float*)d_in[0];
    const float* key   = (const float*)d_in[1];
    const float* W     = (const float*)d_in[2];
    // d_in[3] = head_idx (unused)

    int n_pos = in_sizes[0] / D;        // B*L = 8192
    (void)ws_size; (void)out_size; (void)n_in;

    int* q_code = (int*)d_ws;                                 // n_pos ints
    unsigned char* kperm = (unsigned char*)(q_code + n_pos);  // n_pos bytes

    {
        int total = 2 * n_pos;          // 16384 positions, 64-thread blocks
        code_kernel<<<(total + 63) / 64, 64, 0, stream>>>(query, key, W,
                                                          q_code, kperm, n_pos);
    }
    {
        // one wave per 8 queries, 4 waves per block -> 256 blocks
        scan_emit_kernel<<<n_pos / 32, 256, 0, stream>>>(q_code,
                                                         (const unsigned int*)kperm,
                                                         (int*)d_out);
    }
}

// Round 9
// 74.437 us; speedup vs baseline: 1.9798x; 1.1262x over previous
//
#include <hip/hip_runtime.h>

#define D 64
#define H 8
#define LSEQ 2048
#define KMAX 64
#define NCODES 256   // 2^H

// ---------------------------------------------------------------------------
// Kernel 1: LSH codes for BOTH query and key positions.
// code = sum_h ( (sum_{d: x[d]>0} W[d][h]) > 0 ) << h
// Sequential over d (matches reference accumulation order — absmax has been
// exactly 0 every round; do not re-associate).
// Query codes -> int array. Key codes -> PERMUTED byte array laid out so the
// scan kernel's uint load yields 4 ascending 64-chunks per lane:
//   byte for local pos (i*256 + j*64 + lane) lives at (i*256 + lane*4 + j).
// 64-thread blocks -> 256 blocks, one per CU.
//
// Session lessons baked in:
//  - R7: do NOT fuse via cooperative grid.sync — ~65 µs penalty on gfx950
//    (256 blocks spinning on device-scope atomics across non-coherent XCD
//    L2s). A second launch is ~100x cheaper.
//  - R8: do NOT batch multiple queries per wave in the scan kernel — total
//    work is unchanged but parallelism drops 8x and the per-wave serial
//    critical path dominates (73.9 -> 83.8 µs). TLP wins here.
// ---------------------------------------------------------------------------
__global__ void __launch_bounds__(64)
code_kernel(const float* __restrict__ query,
            const float* __restrict__ key,
            const float* __restrict__ W,
            int* __restrict__ q_code,            // [n_pos]
            unsigned char* __restrict__ kperm,   // [n_pos] permuted bytes
            int n_pos) {
    __shared__ float Ws[D * H];
    for (int i = threadIdx.x; i < D * H; i += blockDim.x) Ws[i] = W[i];
    __syncthreads();

    int t = blockIdx.x * blockDim.x + threadIdx.x;
    if (t >= 2 * n_pos) return;

    const float* xp = (t < n_pos) ? (query + (size_t)t * D)
                                  : (key + (size_t)(t - n_pos) * D);
    float4 s0 = {0.f, 0.f, 0.f, 0.f};
    float4 s1 = {0.f, 0.f, 0.f, 0.f};

    for (int d4 = 0; d4 < D / 4; ++d4) {
        float4 xv = ((const float4*)xp)[d4];
        const float* x4 = (const float*)&xv;
#pragma unroll
        for (int k = 0; k < 4; ++k) {
            if (x4[k] > 0.0f) {
                int d = d4 * 4 + k;
                float4 w0 = *(const float4*)&Ws[d * H + 0];   // LDS broadcast
                float4 w1 = *(const float4*)&Ws[d * H + 4];
                s0.x += w0.x; s0.y += w0.y; s0.z += w0.z; s0.w += w0.w;
                s1.x += w1.x; s1.y += w1.y; s1.z += w1.z; s1.w += w1.w;
            }
        }
    }
    int c = 0;
    c |= (s0.x > 0.0f) ? 1   : 0;
    c |= (s0.y > 0.0f) ? 2   : 0;
    c |= (s0.z > 0.0f) ? 4   : 0;
    c |= (s0.w > 0.0f) ? 8   : 0;
    c |= (s1.x > 0.0f) ? 16  : 0;
    c |= (s1.y > 0.0f) ? 32  : 0;
    c |= (s1.z > 0.0f) ? 64  : 0;
    c |= (s1.w > 0.0f) ? 128 : 0;

    if (t < n_pos) {
        q_code[t] = c;
    } else {
        int kk   = t - n_pos;
        int b    = kk >> 11;            // LSEQ = 2048
        int l    = kk & (LSEQ - 1);
        int lane = l & 63;
        int j    = (l >> 6) & 3;
        int i4   = l >> 8;
        kperm[(b << 11) + (i4 << 8) + (lane << 2) + j] = (unsigned char)c;
    }
}

// ---------------------------------------------------------------------------
// Kernel 2 (fused scan + emit): one WAVE per QUERY (8192 waves, 2048 blocks
// — max TLP). All 8 code-uints (32 codes/lane) are PRELOADED into registers
// (no early exit -> loads fully pipelined), then 32 ballot stream-compaction
// steps rank the first <=KMAX ascending matches into a -1-padded private LDS
// row, emitted as one coalesced 256B store.
// ---------------------------------------------------------------------------
__global__ void __launch_bounds__(256)
scan_emit_kernel(const int* __restrict__ q_code,          // [B*LSEQ]
                 const unsigned int* __restrict__ kperm,  // [B][LSEQ/4]
                 int* __restrict__ out) {                 // [B*LSEQ][KMAX]
    __shared__ int rows[4][KMAX];
    int wave = threadIdx.x >> 6;
    int lane = threadIdx.x & 63;
    int q = blockIdx.x * 4 + wave;       // global query index
    int b = q >> 11;                     // LSEQ = 2048

    int c = q_code[q];                   // wave-uniform broadcast load
    const unsigned int* kp = kperm + (size_t)b * (LSEQ / 4) + lane;
    int* row = rows[wave];
    row[lane] = -1;

    unsigned int v[LSEQ / 256];          // 8 uints = 32 codes per lane
#pragma unroll
    for (int i = 0; i < LSEQ / 256; ++i) v[i] = kp[i * 64];   // all in flight

    unsigned long long lt_mask = (lane == 63) ? 0x7FFFFFFFFFFFFFFFull
                                              : ((1ull << lane) - 1ull);
    int base = 0;
#pragma unroll
    for (int i = 0; i < LSEQ / 256; ++i) {
        unsigned int w = v[i];
#pragma unroll
        for (int j = 0; j < 4; ++j) {
            int ci = (int)((w >> (8 * j)) & 0xFFu);
            unsigned long long mask = __ballot(ci == c);
            if (ci == c) {
                int rank = base + __popcll(mask & lt_mask);
                if (rank < KMAX) row[rank] = i * 256 + j * 64 + lane;
            }
            base += __popcll(mask);
        }
    }
    out[(size_t)q * KMAX + lane] = row[lane];         // 256B coalesced
}

extern "C" void kernel_launch(void* const* d_in, const int* in_sizes, int n_in,
                              void* d_out, int out_size, void* d_ws, size_t ws_size,
                              hipStream_t stream) {
    const float* query = (const float*)d_in[0];
    const float* key   = (const float*)d_in[1];
    const float* W     = (const float*)d_in[2];
    // d_in[3] = head_idx (unused)

    int n_pos = in_sizes[0] / D;        // B*L = 8192
    (void)ws_size; (void)out_size; (void)n_in;

    int* q_code = (int*)d_ws;                                 // n_pos ints
    unsigned char* kperm = (unsigned char*)(q_code + n_pos);  // n_pos bytes

    {
        int total = 2 * n_pos;          // 16384 positions, 64-thread blocks
        code_kernel<<<(total + 63) / 64, 64, 0, stream>>>(query, key, W,
                                                          q_code, kperm, n_pos);
    }
    {
        // one wave per query, 4 waves per block
        scan_emit_kernel<<<n_pos / 4, 256, 0, stream>>>(q_code,
                                                        (const unsigned int*)kperm,
                                                        (int*)d_out);
    }
}